// Round 2
// baseline (291.874 us; speedup 1.0000x reference)
//
#include <hip/hip_runtime.h>
#include <hip/hip_bf16.h>

#define N_NODES 50000
#define N_EDGES 800000
#define N_GRAPHS 64
#define HEADS 4
#define IN_CH 128
#define HID 64
#define F1 256  // HEADS*HID
#define OUT_CH 32
#define F2 128  // HEADS*OUT_CH
#define POOL_SPLITS 16
#define SCAN_B 256
#define SCAN_NB ((N_NODES + SCAN_B - 1) / SCAN_B)  // 196
#define GEMM_GRID ((N_NODES + 127) / 128)          // 391 (32 rows/wave)
#define COUNT_GRID ((N_EDGES + 255) / 256)         // 3125
#define XPACK_GRID (N_NODES * IN_CH / 8 / 256)     // 3125

typedef unsigned short ushortT;
typedef unsigned int uintT;
typedef short v8s __attribute__((ext_vector_type(8)));
typedef float v4f __attribute__((ext_vector_type(4)));
typedef float v2f __attribute__((ext_vector_type(2)));

__device__ __forceinline__ ushortT f2bf(float f) {
    union { float f; unsigned int i; } v; v.f = f;
    unsigned int x = v.i;
    unsigned int r = (x + 0x7fffu + ((x >> 16) & 1u)) >> 16;  // RNE
    return (ushortT)r;
}
__device__ __forceinline__ float bf_lo(uintT w) {
    union { unsigned int i; float f; } v; v.i = w << 16; return v.f;
}
__device__ __forceinline__ float bf_hi(uintT w) {
    union { unsigned int i; float f; } v; v.i = w & 0xffff0000u; return v.f;
}
// fp8 e4m3 (OCP on gfx950) via HW converts
__device__ __forceinline__ unsigned char f2fp8(float f) {
    return (unsigned char)__builtin_amdgcn_cvt_pk_fp8_f32(f, f, 0u, false);
}

// ---- one-time weight pack into bf16 B-fragment image + x fp32->bf16 ----
__device__ __forceinline__ void packW_one(const float* __restrict__ W,
                                          uint4* __restrict__ dst,
                                          int i, int FIN, int FOUT) {
    int KC = FIN / 32;
    int lane = i & 63, g = i >> 6;
    int kc = g % KC, nt = g / KC;
    int n = nt * 16 + (lane & 15);
    int kbase = kc * 32 + (lane >> 4) * 8;
    union { uint4 q; ushortT u[8]; } pk;
#pragma unroll
    for (int j = 0; j < 8; j++) pk.u[j] = f2bf(W[(kbase + j) * FOUT + n]);
    dst[i] = pk.q;
}

__global__ __launch_bounds__(256) void k_pack(
        const float* __restrict__ x, const float* __restrict__ W1,
        const float* __restrict__ W2, uint4* __restrict__ wpk,
        ushortT* __restrict__ xb) {
    int b = blockIdx.x;
    if (b < 32) {
        int i = b * 256 + threadIdx.x;  // 8192 = 4096 (W1) + 4096 (W2)
        if (i < 4096) packW_one(W1, wpk, i, IN_CH, F1);
        else          packW_one(W2, wpk + 4096, i - 4096, F1, F2);
    } else {
        long i = (long)(b - 32) * 256 + threadIdx.x;  // 800000 exactly
        const float4* xf = (const float4*)x + i * 2;
        float4 a = xf[0], c = xf[1];
        union { uint4 q; ushortT u[8]; } pk;
        pk.u[0] = f2bf(a.x); pk.u[1] = f2bf(a.y);
        pk.u[2] = f2bf(a.z); pk.u[3] = f2bf(a.w);
        pk.u[4] = f2bf(c.x); pk.u[5] = f2bf(c.y);
        pk.u[6] = f2bf(c.z); pk.u[7] = f2bf(c.w);
        ((uint4*)xb)[i] = pk.q;
    }
}

// ---- MFMA GEMM body + fused s,d epilogue; 2 row-tiles (32 rows) per wave ----
// NO LDS: W (64 KB, shared by all blocks) is L2-resident; B fragments are read
// straight from the prepacked image via coalesced dwordx4. Removing the 64 KB
// static LDS restores occupancy (2 blocks/CU -> VGPR-limited) for BOTH the
// gemm blocks and the fused edge-count blocks.
template <int FIN, int FOUT>
__device__ __forceinline__ void gemm_body(const ushortT* __restrict__ A,
                                          const uint4* __restrict__ Wpk,
                                          const float* __restrict__ ASrc,
                                          const float* __restrict__ ADst,
                                          unsigned char* __restrict__ out,
                                          float* __restrict__ s_out_g,
                                          float* __restrict__ d_out_g,
                                          int nrows, int bid) {
    constexpr int KC = FIN / 32;
    constexpr int NT = FOUT / 16;
    constexpr int NTH = (FOUT / HEADS) / 16;  // nt tiles per head
    int tid = threadIdx.x;
    int wave = tid >> 6, lane = tid & 63;
    long rowA = (long)bid * 128 + wave * 32;
    long rowB = rowA + 16;
    bool doA = rowA < nrows, doB = rowB < nrows;  // wave-uniform (nrows%16==0)
    if (!doA) return;
    int m = lane & 15, b = lane >> 4;

    v8s afA[KC], afB[KC];
#pragma unroll
    for (int kc = 0; kc < KC; kc++) {
        union { v8s v; uint4 q; } u;
        u.q = *(const uint4*)(A + (rowA + m) * FIN + kc * 32 + b * 8);
        afA[kc] = u.v;
        if (doB) {
            u.q = *(const uint4*)(A + (rowB + m) * FIN + kc * 32 + b * 8);
            afB[kc] = u.v;
        }
    }

    float spA[4] = {0,0,0,0}, dpA[4] = {0,0,0,0};
    float spB[4] = {0,0,0,0}, dpB[4] = {0,0,0,0};
    float skA[4], dkA[4], skB[4], dkB[4];
#pragma unroll
    for (int nt = 0; nt < NT; nt++) {
        v4f cA = {0.f, 0.f, 0.f, 0.f}, cB = {0.f, 0.f, 0.f, 0.f};
#pragma unroll
        for (int kc = 0; kc < KC; kc++) {
            union { v8s v; uint4 q; } bu;
            bu.q = Wpk[(nt * KC + kc) * 64 + lane];
            cA = __builtin_amdgcn_mfma_f32_16x16x32_bf16(afA[kc], bu.v, cA, 0, 0, 0);
            if (doB)
                cB = __builtin_amdgcn_mfma_f32_16x16x32_bf16(afB[kc], bu.v, cB, 0, 0, 0);
        }
        // C/D: col = lane&15, row = (lane>>4)*4 + reg   [measured m89/m91]
        int col = nt * 16 + m;
        float av = ASrc[col], dv = ADst[col];
        long rA = rowA + b * 4;
#pragma unroll
        for (int reg = 0; reg < 4; reg++) {
            out[(rA + reg) * FOUT + col] = f2fp8(cA[reg]);
            spA[reg] += cA[reg] * av;
            dpA[reg] += cA[reg] * dv;
        }
        if (doB) {
            long rB = rowB + b * 4;
#pragma unroll
            for (int reg = 0; reg < 4; reg++) {
                out[(rB + reg) * FOUT + col] = f2fp8(cB[reg]);
                spB[reg] += cB[reg] * av;
                dpB[reg] += cB[reg] * dv;
            }
        }
        if ((nt % NTH) == NTH - 1) {  // head boundary: reduce over 16 m-lanes
#pragma unroll
            for (int o = 1; o < 16; o <<= 1) {
#pragma unroll
                for (int reg = 0; reg < 4; reg++) {
                    spA[reg] += __shfl_xor(spA[reg], o, 64);
                    dpA[reg] += __shfl_xor(dpA[reg], o, 64);
                    spB[reg] += __shfl_xor(spB[reg], o, 64);
                    dpB[reg] += __shfl_xor(dpB[reg], o, 64);
                }
            }
            int hd = nt / NTH;
#pragma unroll
            for (int reg = 0; reg < 4; reg++) {
                if (m == hd) {
                    skA[reg] = spA[reg]; dkA[reg] = dpA[reg];
                    skB[reg] = spB[reg]; dkB[reg] = dpB[reg];
                }
                spA[reg] = 0.f; dpA[reg] = 0.f;
                spB[reg] = 0.f; dpB[reg] = 0.f;
            }
        }
    }
    if (m < HEADS) {
        long rA = rowA + b * 4;
#pragma unroll
        for (int reg = 0; reg < 4; reg++) {
            s_out_g[(rA + reg) * HEADS + m] = skA[reg];
            d_out_g[(rA + reg) * HEADS + m] = dkA[reg];
        }
        if (doB) {
            long rB = rowB + b * 4;
#pragma unroll
            for (int reg = 0; reg < 4; reg++) {
                s_out_g[(rB + reg) * HEADS + m] = skB[reg];
                d_out_g[(rB + reg) * HEADS + m] = dkB[reg];
            }
        }
    }
}

// ---- mega kernel: gemm1 + edge count (count also RECORDS each edge's rank,
// making the later scatter atomic-free; atomics now run at full occupancy
// since the kernel no longer carries a 64 KB LDS allocation) ----
__global__ __launch_bounds__(256) void k_mega1(
        const ushortT* __restrict__ xb, const uint4* __restrict__ wpk,
        const float* __restrict__ asrc1, const float* __restrict__ adst1,
        unsigned char* __restrict__ u_h, float* __restrict__ f_s,
        float* __restrict__ f_d, const int* __restrict__ ei,
        int* __restrict__ counts, int* __restrict__ rank) {
    if (blockIdx.x < GEMM_GRID) {
        gemm_body<IN_CH, F1>(xb, wpk, asrc1, adst1, u_h, f_s, f_d,
                             N_NODES, blockIdx.x);
    } else {
        int e = (blockIdx.x - GEMM_GRID) * 256 + threadIdx.x;
        if (e < N_EDGES) {
            int dst = ei[N_EDGES + e];
            rank[e] = atomicAdd(&counts[dst], 1);
        }
    }
}

__global__ __launch_bounds__(256) void k_gemm2(
        const ushortT* __restrict__ A, const uint4* __restrict__ wpk2,
        const float* __restrict__ asrc2, const float* __restrict__ adst2,
        unsigned char* __restrict__ u_h, float* __restrict__ f_s,
        float* __restrict__ f_d) {
    gemm_body<F1, F2>(A, wpk2, asrc2, adst2, u_h, f_s, f_d,
                      N_NODES, blockIdx.x);
}

// ---- 2-phase exclusive scan (consumers add bbase inline) ----
__global__ void k_scan1(const int* __restrict__ counts, int* __restrict__ offs,
                        int* __restrict__ bsum) {
    __shared__ int sh[SCAN_B];
    int b = blockIdx.x, t = threadIdx.x;
    int i = b * SCAN_B + t;
    int v = (i < N_NODES) ? counts[i] : 0;
    sh[t] = v;
    __syncthreads();
    for (int o = 1; o < SCAN_B; o <<= 1) {
        int add = (t >= o) ? sh[t - o] : 0;
        __syncthreads();
        sh[t] += add;
        __syncthreads();
    }
    if (i < N_NODES) offs[i] = sh[t] - v;  // block-local exclusive
    if (t == SCAN_B - 1) bsum[b] = sh[t];
}

__global__ void k_scan2(const int* __restrict__ bsum, int* __restrict__ bbase,
                        int* __restrict__ offs, const int* __restrict__ batch,
                        int* __restrict__ bounds) {
    __shared__ int sh[SCAN_B];
    int t = threadIdx.x;
    int v = (t < SCAN_NB) ? bsum[t] : 0;
    sh[t] = v;
    __syncthreads();
    for (int o = 1; o < SCAN_B; o <<= 1) {
        int add = (t >= o) ? sh[t - o] : 0;
        __syncthreads();
        sh[t] += add;
        __syncthreads();
    }
    if (t < SCAN_NB) bbase[t] = sh[t] - v;      // exclusive base per block
    if (t == SCAN_B - 1) offs[N_NODES] = sh[t]; // grand total (= N_EDGES)
    // fused: graph boundaries via binary search on sorted batch
    if (t <= N_GRAPHS) {
        int lo = 0, hi = N_NODES;
        while (lo < hi) {
            int mid = (lo + hi) >> 1;
            if (batch[mid] < t) lo = mid + 1; else hi = mid;
        }
        bounds[t] = lo;
    }
}

// ---- scatter: ATOMIC-FREE (rank precomputed during count) ----
__global__ void k_scatter(const int* __restrict__ ei, const int* __restrict__ offs,
                          const int* __restrict__ bbase, const int* __restrict__ rank,
                          int* __restrict__ csr_src) {
    int e = blockIdx.x * blockDim.x + threadIdx.x;
    if (e >= N_EDGES) return;
    int src = ei[e], dst = ei[N_EDGES + e];
    int pos = offs[dst] + bbase[dst >> 8] + rank[e];
    csr_src[pos] = src;
}

// ---- fused segment-softmax + aggregation: one node per wave, NO barriers ----
// hb is fp8 e4m3: halves gather bytes/edge AND the table size (L2 reach).
// Output stays bf16 (feeds MFMA gemm2 / pool).
template <int H, int C, int VEC, int WPB, int CHUNK>
__global__ __launch_bounds__(64 * WPB) void k_agg(
        const unsigned char* __restrict__ hb, const float* __restrict__ s,
        const float* __restrict__ d, const int* __restrict__ offs,
        const int* __restrict__ bbase, const int* __restrict__ csr_src,
        const float* __restrict__ bias, ushortT* __restrict__ xout) {
    static_assert(H == 4, "H=4 assumed");
    constexpr int F = H * C;
    constexpr int TPN = F / VEC;
    static_assert(TPN == 64, "one wave per node");
    __shared__ int lsrc[WPB][CHUNK];
    __shared__ float lex[WPB][CHUNK * H];
    int wv = threadIdx.x >> 6;
    int n = blockIdx.x * WPB + wv;
    if (n >= N_NODES) return;
    int t = threadIdx.x & 63;
    int h = t / (C / VEC);
    int beg = offs[n] + bbase[n >> 8];
    int np1 = n + 1;
    int end = (np1 < N_NODES) ? offs[np1] + bbase[np1 >> 8] : offs[N_NODES];
    float4 dn = *(const float4*)(d + n * 4);

    const uintT* hb4 = (const uintT*)hb;    // VEC==4: 4 fp8 per lane
    const ushortT* hb2s = (const ushortT*)hb;  // VEC==2: 2 fp8 per lane

    // implicit self-loop: init sumex/acc from own s,d,h (outside the hot loop)
    float4 svn = *(const float4*)(s + n * 4);
    float ssel = (h == 0) ? svn.x : (h == 1) ? svn.y : (h == 2) ? svn.z : svn.w;
    float dsel = (h == 0) ? dn.x : (h == 1) ? dn.y : (h == 2) ? dn.z : dn.w;
    float es = ssel + dsel; es = es > 0.f ? es : 0.2f * es;
    float exs = __expf(es);
    float sumex = exs;
    float acc[VEC];
    if (VEC == 4) {
        uintT w = hb4[(long)n * TPN + t];
        v2f p0 = __builtin_amdgcn_cvt_pk_f32_fp8(w, false);
        v2f p1 = __builtin_amdgcn_cvt_pk_f32_fp8(w, true);
        acc[0] = exs * p0.x; acc[1] = exs * p0.y;
        acc[2] = exs * p1.x; acc[3] = exs * p1.y;
    } else {
        uintT w = hb2s[(long)n * TPN + t];
        v2f p0 = __builtin_amdgcn_cvt_pk_f32_fp8(w, false);
        acc[0] = exs * p0.x; acc[1] = exs * p0.y;
    }

    for (int base = beg; base < end; base += CHUNK) {
        int cnt = min(CHUNK, end - base);
        // phase 1: stage src ids + per-head exp into this wave's LDS slice
        for (int i = t; i < cnt; i += 64) {
            int sn = csr_src[base + i];
            lsrc[wv][i] = sn;
            float4 sv = *(const float4*)(s + sn * 4);
            float e0 = sv.x + dn.x; e0 = e0 > 0.f ? e0 : 0.2f * e0;
            float e1 = sv.y + dn.y; e1 = e1 > 0.f ? e1 : 0.2f * e1;
            float e2 = sv.z + dn.z; e2 = e2 > 0.f ? e2 : 0.2f * e2;
            float e3 = sv.w + dn.w; e3 = e3 > 0.f ? e3 : 0.2f * e3;
            float4 exv = { __expf(e0), __expf(e1), __expf(e2), __expf(e3) };
            *(float4*)&lex[wv][i * 4] = exv;
        }
        // intra-wave LDS write->read ordering (no block barrier needed)
        asm volatile("s_waitcnt lgkmcnt(0)" ::: "memory");
        // phase 2: accumulate (unroll 8: fp8 halved bytes/edge, MLP-limited)
#pragma unroll 8
        for (int i = 0; i < cnt; i++) {
            float ex = lex[wv][i * H + h];
            int sn = lsrc[wv][i];
            sumex += ex;
            if (VEC == 4) {
                uintT w = hb4[(long)sn * TPN + t];
                v2f p0 = __builtin_amdgcn_cvt_pk_f32_fp8(w, false);
                v2f p1 = __builtin_amdgcn_cvt_pk_f32_fp8(w, true);
                acc[0] += ex * p0.x;
                acc[1] += ex * p0.y;
                acc[2] += ex * p1.x;
                acc[3] += ex * p1.y;
            } else {
                uintT w = hb2s[(long)sn * TPN + t];
                v2f p0 = __builtin_amdgcn_cvt_pk_f32_fp8(w, false);
                acc[0] += ex * p0.x;
                acc[1] += ex * p0.y;
            }
        }
        asm volatile("" ::: "memory");
    }
    float inv = 1.f / (sumex + 1e-16f);
    float o[VEC];
#pragma unroll
    for (int j = 0; j < VEC; j++)
        o[j] = fmaxf(acc[j] * inv + bias[t * VEC + j], 0.f);
    if (VEC == 4) {
        uint2 pk;
        pk.x = (uintT)f2bf(o[0]) | ((uintT)f2bf(o[1]) << 16);
        pk.y = (uintT)f2bf(o[2]) | ((uintT)f2bf(o[3]) << 16);
        ((uint2*)xout)[(long)n * TPN + t] = pk;
    } else {
        uintT pk = (uintT)f2bf(o[0]) | ((uintT)f2bf(o[1]) << 16);
        ((uintT*)xout)[(long)n * TPN + t] = pk;
    }
}

// ---- pool partials over bf16 x2: block (g,s) sums a contiguous slice ----
__global__ void k_pool_partial(const ushortT* __restrict__ x2, const int* __restrict__ bounds,
                               float* __restrict__ partial) {
    int g = blockIdx.x, s = blockIdx.y;
    int t = threadIdx.x;  // F2 threads
    int n0 = bounds[g], n1 = bounds[g + 1];
    int len = n1 - n0;
    int a = n0 + (int)((long)len * s / POOL_SPLITS);
    int b = n0 + (int)((long)len * (s + 1) / POOL_SPLITS);
    float acc = 0.f;
    for (int n = a; n < b; n++) acc += bf_lo((uintT)x2[(long)n * F2 + t]);
    partial[((long)g * POOL_SPLITS + s) * F2 + t] = acc;
}

// ---- head: block per graph — reduce partials, mean, logits, softmax ----
__global__ void k_head(const float* __restrict__ partial, const int* __restrict__ bounds,
                       const float* __restrict__ Wout, const float* __restrict__ bout,
                       float* __restrict__ out) {
    __shared__ float red0[F2], red1[F2];
    int g = blockIdx.x;
    int t = threadIdx.x;
    int cntN = bounds[g + 1] - bounds[g];
    float cnt = fmaxf((float)cntN, 1.0f);
    float sum = 0.f;
    for (int s = 0; s < POOL_SPLITS; s++)
        sum += partial[((long)g * POOL_SPLITS + s) * F2 + t];
    float p = sum / cnt;
    red0[t] = p * Wout[t * 2 + 0];
    red1[t] = p * Wout[t * 2 + 1];
    __syncthreads();
    for (int off = F2 / 2; off > 0; off >>= 1) {
        if (t < off) { red0[t] += red0[t + off]; red1[t] += red1[t + off]; }
        __syncthreads();
    }
    if (t == 0) {
        float l0 = red0[0] + bout[0];
        float l1 = red1[0] + bout[1];
        float m = fmaxf(l0, l1);
        float e0 = __expf(l0 - m), e1 = __expf(l1 - m);
        float inv = 1.f / (e0 + e1);
        out[g * 2 + 0] = e0 * inv;
        out[g * 2 + 1] = e1 * inv;
    }
}

extern "C" void kernel_launch(void* const* d_in, const int* in_sizes, int n_in,
                              void* d_out, int out_size, void* d_ws, size_t ws_size,
                              hipStream_t stream) {
    const float* x     = (const float*)d_in[0];
    const int*   ei    = (const int*)d_in[1];
    const int*   batch = (const int*)d_in[2];
    const float* W1    = (const float*)d_in[3];
    const float* asrc1 = (const float*)d_in[4];
    const float* adst1 = (const float*)d_in[5];
    const float* b1    = (const float*)d_in[6];
    const float* W2    = (const float*)d_in[7];
    const float* asrc2 = (const float*)d_in[8];
    const float* adst2 = (const float*)d_in[9];
    const float* b2    = (const float*)d_in[10];
    const float* Wout  = (const float*)d_in[11];
    const float* bout  = (const float*)d_in[12];

    char* ws = (char*)d_ws;
    size_t off = 0;
    auto alloc = [&](size_t bytes) -> void* {
        void* p = ws + off;
        off += (bytes + 255) / 256 * 256;
        return p;
    };
    unsigned char* u_h = (unsigned char*)alloc((size_t)N_NODES * F1);  // fp8 h (both layers)
    ushortT* u_x1  = (ushortT*)alloc(sizeof(ushortT) * (size_t)N_NODES * F1);
    ushortT* u_x2  = (ushortT*)alloc(sizeof(ushortT) * (size_t)N_NODES * F2);
    ushortT* xb    = (ushortT*)alloc(sizeof(ushortT) * (size_t)N_NODES * IN_CH);
    uint4*   wpk   = (uint4*)alloc(sizeof(uint4) * 8192);  // W1|W2 fragment images
    float*   f_s   = (float*)alloc(sizeof(float) * (size_t)N_NODES * HEADS);
    float*   f_d   = (float*)alloc(sizeof(float) * (size_t)N_NODES * HEADS);
    int*     i_cnt = (int*)alloc(sizeof(int) * (size_t)N_NODES);
    int*     i_off = (int*)alloc(sizeof(int) * (size_t)(N_NODES + 1));
    int*     i_rnk = (int*)alloc(sizeof(int) * (size_t)N_EDGES);
    int*     i_csr = (int*)alloc(sizeof(int) * (size_t)N_EDGES);
    int*     i_bnd = (int*)alloc(sizeof(int) * (size_t)(N_GRAPHS + 1));
    int*     i_bs  = (int*)alloc(sizeof(int) * SCAN_NB);
    int*     i_bb  = (int*)alloc(sizeof(int) * SCAN_NB);
    float*   f_prt = (float*)alloc(sizeof(float) * (size_t)N_GRAPHS * POOL_SPLITS * F2);
    (void)ws_size; (void)in_sizes; (void)n_in; (void)out_size;

    hipMemsetAsync(i_cnt, 0, sizeof(int) * N_NODES, stream);

    // one-time packs: W1/W2 -> bf16 fragment image, x -> bf16 rows
    k_pack<<<32 + XPACK_GRID, 256, 0, stream>>>(x, W1, W2, wpk, xb);

    // mega: gemm1 (prepacked W, no LDS, fp8 out) + CSR count-with-rank
    k_mega1<<<GEMM_GRID + COUNT_GRID, 256, 0, stream>>>(
        xb, wpk, asrc1, adst1, u_h, f_s, f_d, ei, i_cnt, i_rnk);

    // 2-phase scan (+bounds); atomic-free scatter using precomputed ranks
    k_scan1<<<SCAN_NB, SCAN_B, 0, stream>>>(i_cnt, i_off, i_bs);
    k_scan2<<<1, SCAN_B, 0, stream>>>(i_bs, i_bb, i_off, batch, i_bnd);
    k_scatter<<<COUNT_GRID, 256, 0, stream>>>(ei, i_off, i_bb, i_rnk, i_csr);

    int agg_grid = (N_NODES + 3) / 4;  // 1 node per wave, 4 waves per block

    // Layer 1 aggregation (fp8 gather)
    k_agg<HEADS, HID, 4, 4, 128><<<agg_grid, 256, 0, stream>>>(
        u_h, f_s, f_d, i_off, i_bb, i_csr, b1, u_x1);

    // Layer 2
    k_gemm2<<<GEMM_GRID, 256, 0, stream>>>(u_x1, wpk + 4096, asrc2, adst2,
                                           u_h, f_s, f_d);
    k_agg<HEADS, OUT_CH, 2, 4, 128><<<agg_grid, 256, 0, stream>>>(
        u_h, f_s, f_d, i_off, i_bb, i_csr, b2, u_x2);

    // Pool (1024 blocks, machine-filling) + tiny head
    dim3 pgrid(N_GRAPHS, POOL_SPLITS);
    k_pool_partial<<<pgrid, F2, 0, stream>>>(u_x2, i_bnd, f_prt);
    k_head<<<N_GRAPHS, F2, 0, stream>>>(f_prt, i_bnd, Wout, bout, (float*)d_out);
}

// Round 3
// 270.252 us; speedup vs baseline: 1.0800x; 1.0800x over previous
//
#include <hip/hip_runtime.h>
#include <hip/hip_bf16.h>

#define N_NODES 50000
#define N_EDGES 800000
#define N_GRAPHS 64
#define HEADS 4
#define IN_CH 128
#define HID 64
#define F1 256  // HEADS*HID
#define OUT_CH 32
#define F2 128  // HEADS*OUT_CH
#define POOL_SPLITS 16
#define SCAN_B 256
#define SCAN_NB ((N_NODES + SCAN_B - 1) / SCAN_B)  // 196
#define GEMM_GRID ((N_NODES + 127) / 128)          // 391 (32 rows/wave)
#define COUNT_GRID ((N_EDGES + 255) / 256)         // 3125
#define XPACK_GRID (N_NODES * IN_CH / 8 / 256)     // 3125

typedef unsigned short ushortT;
typedef unsigned int uintT;
typedef short v8s __attribute__((ext_vector_type(8)));
typedef float v4f __attribute__((ext_vector_type(4)));
typedef float v2f __attribute__((ext_vector_type(2)));

__device__ __forceinline__ ushortT f2bf(float f) {
    union { float f; unsigned int i; } v; v.f = f;
    unsigned int x = v.i;
    unsigned int r = (x + 0x7fffu + ((x >> 16) & 1u)) >> 16;  // RNE
    return (ushortT)r;
}
__device__ __forceinline__ float bf_lo(uintT w) {
    union { unsigned int i; float f; } v; v.i = w << 16; return v.f;
}
__device__ __forceinline__ float bf_hi(uintT w) {
    union { unsigned int i; float f; } v; v.i = w & 0xffff0000u; return v.f;
}
// fp8 e4m3 (OCP on gfx950) via HW converts
__device__ __forceinline__ unsigned char f2fp8(float f) {
    return (unsigned char)__builtin_amdgcn_cvt_pk_fp8_f32(f, f, 0u, false);
}

// ---- one-time weight pack into bf16 B-fragment image + x fp32->bf16 ----
__device__ __forceinline__ void packW_one(const float* __restrict__ W,
                                          uint4* __restrict__ dst,
                                          int i, int FIN, int FOUT) {
    int KC = FIN / 32;
    int lane = i & 63, g = i >> 6;
    int kc = g % KC, nt = g / KC;
    int n = nt * 16 + (lane & 15);
    int kbase = kc * 32 + (lane >> 4) * 8;
    union { uint4 q; ushortT u[8]; } pk;
#pragma unroll
    for (int j = 0; j < 8; j++) pk.u[j] = f2bf(W[(kbase + j) * FOUT + n]);
    dst[i] = pk.q;
}

__global__ __launch_bounds__(256) void k_pack(
        const float* __restrict__ x, const float* __restrict__ W1,
        const float* __restrict__ W2, uint4* __restrict__ wpk,
        ushortT* __restrict__ xb) {
    int b = blockIdx.x;
    if (b < 32) {
        int i = b * 256 + threadIdx.x;  // 8192 = 4096 (W1) + 4096 (W2)
        if (i < 4096) packW_one(W1, wpk, i, IN_CH, F1);
        else          packW_one(W2, wpk + 4096, i - 4096, F1, F2);
    } else {
        long i = (long)(b - 32) * 256 + threadIdx.x;  // 800000 exactly
        const float4* xf = (const float4*)x + i * 2;
        float4 a = xf[0], c = xf[1];
        union { uint4 q; ushortT u[8]; } pk;
        pk.u[0] = f2bf(a.x); pk.u[1] = f2bf(a.y);
        pk.u[2] = f2bf(a.z); pk.u[3] = f2bf(a.w);
        pk.u[4] = f2bf(c.x); pk.u[5] = f2bf(c.y);
        pk.u[6] = f2bf(c.z); pk.u[7] = f2bf(c.w);
        ((uint4*)xb)[i] = pk.q;
    }
}

// ---- MFMA GEMM body + fused s,d epilogue; 2 row-tiles (32 rows) per wave ----
// NO LDS: W (64 KB, shared by all blocks) is L2-resident; B fragments are read
// straight from the prepacked image via coalesced dwordx4.
template <int FIN, int FOUT>
__device__ __forceinline__ void gemm_body(const ushortT* __restrict__ A,
                                          const uint4* __restrict__ Wpk,
                                          const float* __restrict__ ASrc,
                                          const float* __restrict__ ADst,
                                          unsigned char* __restrict__ out,
                                          float* __restrict__ s_out_g,
                                          float* __restrict__ d_out_g,
                                          int nrows, int bid) {
    constexpr int KC = FIN / 32;
    constexpr int NT = FOUT / 16;
    constexpr int NTH = (FOUT / HEADS) / 16;  // nt tiles per head
    int tid = threadIdx.x;
    int wave = tid >> 6, lane = tid & 63;
    long rowA = (long)bid * 128 + wave * 32;
    long rowB = rowA + 16;
    bool doA = rowA < nrows, doB = rowB < nrows;  // wave-uniform (nrows%16==0)
    if (!doA) return;
    int m = lane & 15, b = lane >> 4;

    v8s afA[KC], afB[KC];
#pragma unroll
    for (int kc = 0; kc < KC; kc++) {
        union { v8s v; uint4 q; } u;
        u.q = *(const uint4*)(A + (rowA + m) * FIN + kc * 32 + b * 8);
        afA[kc] = u.v;
        if (doB) {
            u.q = *(const uint4*)(A + (rowB + m) * FIN + kc * 32 + b * 8);
            afB[kc] = u.v;
        }
    }

    float spA[4] = {0,0,0,0}, dpA[4] = {0,0,0,0};
    float spB[4] = {0,0,0,0}, dpB[4] = {0,0,0,0};
    float skA[4], dkA[4], skB[4], dkB[4];
#pragma unroll
    for (int nt = 0; nt < NT; nt++) {
        v4f cA = {0.f, 0.f, 0.f, 0.f}, cB = {0.f, 0.f, 0.f, 0.f};
#pragma unroll
        for (int kc = 0; kc < KC; kc++) {
            union { v8s v; uint4 q; } bu;
            bu.q = Wpk[(nt * KC + kc) * 64 + lane];
            cA = __builtin_amdgcn_mfma_f32_16x16x32_bf16(afA[kc], bu.v, cA, 0, 0, 0);
            if (doB)
                cB = __builtin_amdgcn_mfma_f32_16x16x32_bf16(afB[kc], bu.v, cB, 0, 0, 0);
        }
        // C/D: col = lane&15, row = (lane>>4)*4 + reg   [measured m89/m91]
        int col = nt * 16 + m;
        float av = ASrc[col], dv = ADst[col];
        long rA = rowA + b * 4;
#pragma unroll
        for (int reg = 0; reg < 4; reg++) {
            out[(rA + reg) * FOUT + col] = f2fp8(cA[reg]);
            spA[reg] += cA[reg] * av;
            dpA[reg] += cA[reg] * dv;
        }
        if (doB) {
            long rB = rowB + b * 4;
#pragma unroll
            for (int reg = 0; reg < 4; reg++) {
                out[(rB + reg) * FOUT + col] = f2fp8(cB[reg]);
                spB[reg] += cB[reg] * av;
                dpB[reg] += cB[reg] * dv;
            }
        }
        if ((nt % NTH) == NTH - 1) {  // head boundary: reduce over 16 m-lanes
#pragma unroll
            for (int o = 1; o < 16; o <<= 1) {
#pragma unroll
                for (int reg = 0; reg < 4; reg++) {
                    spA[reg] += __shfl_xor(spA[reg], o, 64);
                    dpA[reg] += __shfl_xor(dpA[reg], o, 64);
                    spB[reg] += __shfl_xor(spB[reg], o, 64);
                    dpB[reg] += __shfl_xor(dpB[reg], o, 64);
                }
            }
            int hd = nt / NTH;
#pragma unroll
            for (int reg = 0; reg < 4; reg++) {
                if (m == hd) {
                    skA[reg] = spA[reg]; dkA[reg] = dpA[reg];
                    skB[reg] = spB[reg]; dkB[reg] = dpB[reg];
                }
                spA[reg] = 0.f; dpA[reg] = 0.f;
                spB[reg] = 0.f; dpB[reg] = 0.f;
            }
        }
    }
    if (m < HEADS) {
        long rA = rowA + b * 4;
#pragma unroll
        for (int reg = 0; reg < 4; reg++) {
            s_out_g[(rA + reg) * HEADS + m] = skA[reg];
            d_out_g[(rA + reg) * HEADS + m] = dkA[reg];
        }
        if (doB) {
            long rB = rowB + b * 4;
#pragma unroll
            for (int reg = 0; reg < 4; reg++) {
                s_out_g[(rB + reg) * HEADS + m] = skB[reg];
                d_out_g[(rB + reg) * HEADS + m] = dkB[reg];
            }
        }
    }
}

// ---- mega kernel: gemm1 + edge count (count also RECORDS each edge's rank,
// making the later scatter atomic-free) ----
__global__ __launch_bounds__(256) void k_mega1(
        const ushortT* __restrict__ xb, const uint4* __restrict__ wpk,
        const float* __restrict__ asrc1, const float* __restrict__ adst1,
        unsigned char* __restrict__ u_h, float* __restrict__ f_s,
        float* __restrict__ f_d, const int* __restrict__ ei,
        int* __restrict__ counts, int* __restrict__ rank) {
    if (blockIdx.x < GEMM_GRID) {
        gemm_body<IN_CH, F1>(xb, wpk, asrc1, adst1, u_h, f_s, f_d,
                             N_NODES, blockIdx.x);
    } else {
        int e = (blockIdx.x - GEMM_GRID) * 256 + threadIdx.x;
        if (e < N_EDGES) {
            int dst = ei[N_EDGES + e];
            rank[e] = atomicAdd(&counts[dst], 1);
        }
    }
}

__global__ __launch_bounds__(256) void k_gemm2(
        const ushortT* __restrict__ A, const uint4* __restrict__ wpk2,
        const float* __restrict__ asrc2, const float* __restrict__ adst2,
        unsigned char* __restrict__ u_h, float* __restrict__ f_s,
        float* __restrict__ f_d) {
    gemm_body<F1, F2>(A, wpk2, asrc2, adst2, u_h, f_s, f_d,
                      N_NODES, blockIdx.x);
}

// ---- 2-phase exclusive scan (consumers add bbase inline) ----
__global__ void k_scan1(const int* __restrict__ counts, int* __restrict__ offs,
                        int* __restrict__ bsum) {
    __shared__ int sh[SCAN_B];
    int b = blockIdx.x, t = threadIdx.x;
    int i = b * SCAN_B + t;
    int v = (i < N_NODES) ? counts[i] : 0;
    sh[t] = v;
    __syncthreads();
    for (int o = 1; o < SCAN_B; o <<= 1) {
        int add = (t >= o) ? sh[t - o] : 0;
        __syncthreads();
        sh[t] += add;
        __syncthreads();
    }
    if (i < N_NODES) offs[i] = sh[t] - v;  // block-local exclusive
    if (t == SCAN_B - 1) bsum[b] = sh[t];
}

__global__ void k_scan2(const int* __restrict__ bsum, int* __restrict__ bbase,
                        int* __restrict__ offs, const int* __restrict__ batch,
                        int* __restrict__ bounds) {
    __shared__ int sh[SCAN_B];
    int t = threadIdx.x;
    int v = (t < SCAN_NB) ? bsum[t] : 0;
    sh[t] = v;
    __syncthreads();
    for (int o = 1; o < SCAN_B; o <<= 1) {
        int add = (t >= o) ? sh[t - o] : 0;
        __syncthreads();
        sh[t] += add;
        __syncthreads();
    }
    if (t < SCAN_NB) bbase[t] = sh[t] - v;      // exclusive base per block
    if (t == SCAN_B - 1) offs[N_NODES] = sh[t]; // grand total (= N_EDGES)
    // fused: graph boundaries via binary search on sorted batch
    if (t <= N_GRAPHS) {
        int lo = 0, hi = N_NODES;
        while (lo < hi) {
            int mid = (lo + hi) >> 1;
            if (batch[mid] < t) lo = mid + 1; else hi = mid;
        }
        bounds[t] = lo;
    }
}

// ---- scatter: ATOMIC-FREE (rank precomputed during count) ----
__global__ void k_scatter(const int* __restrict__ ei, const int* __restrict__ offs,
                          const int* __restrict__ bbase, const int* __restrict__ rank,
                          int* __restrict__ csr_src) {
    int e = blockIdx.x * blockDim.x + threadIdx.x;
    if (e >= N_EDGES) return;
    int src = ei[e], dst = ei[N_EDGES + e];
    int pos = offs[dst] + bbase[dst >> 8] + rank[e];
    csr_src[pos] = src;
}

// ---- fused segment-softmax + aggregation: TWO nodes per wave (32 lanes
// each), no barriers. Mean degree is only 16, so a 64-lane wave per node
// left phase 1 75% lane-idle and phase 2 pure serial issue. 2 nodes/wave
// halves wave-instructions per edge (the measured bottleneck: VALU issue,
// not FLOPs or BW). Degree mismatch between the pair is predicated (ex=0).
// C/VEC == 8 for both layers so head index is tl>>3 in both. ----
template <int C, int VEC, int WPB, int CHUNK>
__global__ __launch_bounds__(64 * WPB) void k_agg(
        const unsigned char* __restrict__ hb, const float* __restrict__ s,
        const float* __restrict__ d, const int* __restrict__ offs,
        const int* __restrict__ bbase, const int* __restrict__ csr_src,
        const float* __restrict__ bias, ushortT* __restrict__ xout) {
    constexpr int F = HEADS * C;
    constexpr int TPN = F / VEC;  // lanes per node
    static_assert(TPN == 32, "two nodes per wave");
    static_assert(C / VEC == 8, "head = tl>>3");
    static_assert(N_NODES % (WPB * 2) == 0, "exact grid");
    __shared__ int lsrc[WPB][2][CHUNK];
    __shared__ float lex[WPB][2][CHUNK * HEADS];
    int wv = threadIdx.x >> 6;
    int t = threadIdx.x & 63;
    int half = t >> 5, tl = t & 31;
    int n = (blockIdx.x * WPB + wv) * 2 + half;
    int h = tl >> 3;
    int beg = offs[n] + bbase[n >> 8];
    int np1 = n + 1;
    int end = (np1 < N_NODES) ? offs[np1] + bbase[np1 >> 8] : offs[N_NODES];
    float4 dn = *(const float4*)(d + n * 4);

    // implicit self-loop: init sumex/acc from own s,d,h (outside the hot loop)
    float4 svn = *(const float4*)(s + n * 4);
    float ssel = (h == 0) ? svn.x : (h == 1) ? svn.y : (h == 2) ? svn.z : svn.w;
    float dsel = (h == 0) ? dn.x : (h == 1) ? dn.y : (h == 2) ? dn.z : dn.w;
    float es = ssel + dsel; es = es > 0.f ? es : 0.2f * es;
    float exs = __expf(es);
    float sumex = exs;
    float acc[VEC];
    if (VEC == 8) {
        uint2 w = ((const uint2*)hb)[(long)n * TPN + tl];
        v2f p0 = __builtin_amdgcn_cvt_pk_f32_fp8(w.x, false);
        v2f p1 = __builtin_amdgcn_cvt_pk_f32_fp8(w.x, true);
        v2f p2 = __builtin_amdgcn_cvt_pk_f32_fp8(w.y, false);
        v2f p3 = __builtin_amdgcn_cvt_pk_f32_fp8(w.y, true);
        acc[0] = exs * p0.x; acc[1] = exs * p0.y;
        acc[2] = exs * p1.x; acc[3] = exs * p1.y;
        acc[4] = exs * p2.x; acc[5] = exs * p2.y;
        acc[6] = exs * p3.x; acc[7] = exs * p3.y;
    } else {
        uintT w = ((const uintT*)hb)[(long)n * TPN + tl];
        v2f p0 = __builtin_amdgcn_cvt_pk_f32_fp8(w, false);
        v2f p1 = __builtin_amdgcn_cvt_pk_f32_fp8(w, true);
        acc[0] = exs * p0.x; acc[1] = exs * p0.y;
        acc[2] = exs * p1.x; acc[3] = exs * p1.y;
    }

    int tot = end - beg;                      // uniform within a half
    int totO = __shfl_xor(tot, 32, 64);       // other half's count
    int maxTot = max(tot, totO);
    for (int base = 0; base < maxTot; base += CHUNK) {
        int cnt = min(CHUNK, tot - base); if (cnt < 0) cnt = 0;
        int cntW = min(CHUNK, maxTot - base);  // wave-uniform loop bound
        // phase 1: each half stages its own node's edges (32 lanes active)
        for (int i = tl; i < cnt; i += TPN) {
            int sn = csr_src[beg + base + i];
            lsrc[wv][half][i] = sn;
            float4 sv = *(const float4*)(s + sn * 4);
            float e0 = sv.x + dn.x; e0 = e0 > 0.f ? e0 : 0.2f * e0;
            float e1 = sv.y + dn.y; e1 = e1 > 0.f ? e1 : 0.2f * e1;
            float e2 = sv.z + dn.z; e2 = e2 > 0.f ? e2 : 0.2f * e2;
            float e3 = sv.w + dn.w; e3 = e3 > 0.f ? e3 : 0.2f * e3;
            float4 exv = { __expf(e0), __expf(e1), __expf(e2), __expf(e3) };
            *(float4*)&lex[wv][half][i * 4] = exv;
        }
        // intra-wave LDS write->read ordering (no block barrier needed)
        asm volatile("s_waitcnt lgkmcnt(0)" ::: "memory");
        // phase 2: both halves accumulate in lockstep; shorter half padded
        // with ex=0 / sn=0 (branchless, finite data -> adds exact 0)
#pragma unroll 4
        for (int i = 0; i < cntW; i++) {
            bool act = i < cnt;
            float ex = act ? lex[wv][half][i * 4 + h] : 0.f;
            int sn = act ? lsrc[wv][half][i] : 0;
            sumex += ex;
            if (VEC == 8) {
                uint2 w = ((const uint2*)hb)[(long)sn * TPN + tl];
                v2f p0 = __builtin_amdgcn_cvt_pk_f32_fp8(w.x, false);
                v2f p1 = __builtin_amdgcn_cvt_pk_f32_fp8(w.x, true);
                v2f p2 = __builtin_amdgcn_cvt_pk_f32_fp8(w.y, false);
                v2f p3 = __builtin_amdgcn_cvt_pk_f32_fp8(w.y, true);
                acc[0] += ex * p0.x; acc[1] += ex * p0.y;
                acc[2] += ex * p1.x; acc[3] += ex * p1.y;
                acc[4] += ex * p2.x; acc[5] += ex * p2.y;
                acc[6] += ex * p3.x; acc[7] += ex * p3.y;
            } else {
                uintT w = ((const uintT*)hb)[(long)sn * TPN + tl];
                v2f p0 = __builtin_amdgcn_cvt_pk_f32_fp8(w, false);
                v2f p1 = __builtin_amdgcn_cvt_pk_f32_fp8(w, true);
                acc[0] += ex * p0.x; acc[1] += ex * p0.y;
                acc[2] += ex * p1.x; acc[3] += ex * p1.y;
            }
        }
        asm volatile("" ::: "memory");
    }
    float inv = 1.f / (sumex + 1e-16f);
    float o[VEC];
#pragma unroll
    for (int j = 0; j < VEC; j++)
        o[j] = fmaxf(acc[j] * inv + bias[tl * VEC + j], 0.f);
    if (VEC == 8) {
        uint4 pk;
        pk.x = (uintT)f2bf(o[0]) | ((uintT)f2bf(o[1]) << 16);
        pk.y = (uintT)f2bf(o[2]) | ((uintT)f2bf(o[3]) << 16);
        pk.z = (uintT)f2bf(o[4]) | ((uintT)f2bf(o[5]) << 16);
        pk.w = (uintT)f2bf(o[6]) | ((uintT)f2bf(o[7]) << 16);
        ((uint4*)xout)[(long)n * TPN + tl] = pk;
    } else {
        uint2 pk;
        pk.x = (uintT)f2bf(o[0]) | ((uintT)f2bf(o[1]) << 16);
        pk.y = (uintT)f2bf(o[2]) | ((uintT)f2bf(o[3]) << 16);
        ((uint2*)xout)[(long)n * TPN + tl] = pk;
    }
}

// ---- pool partials over bf16 x2: block (g,s) sums a contiguous slice ----
__global__ void k_pool_partial(const ushortT* __restrict__ x2, const int* __restrict__ bounds,
                               float* __restrict__ partial) {
    int g = blockIdx.x, s = blockIdx.y;
    int t = threadIdx.x;  // F2 threads
    int n0 = bounds[g], n1 = bounds[g + 1];
    int len = n1 - n0;
    int a = n0 + (int)((long)len * s / POOL_SPLITS);
    int b = n0 + (int)((long)len * (s + 1) / POOL_SPLITS);
    float acc = 0.f;
    for (int n = a; n < b; n++) acc += bf_lo((uintT)x2[(long)n * F2 + t]);
    partial[((long)g * POOL_SPLITS + s) * F2 + t] = acc;
}

// ---- head: block per graph — reduce partials, mean, logits, softmax ----
__global__ void k_head(const float* __restrict__ partial, const int* __restrict__ bounds,
                       const float* __restrict__ Wout, const float* __restrict__ bout,
                       float* __restrict__ out) {
    __shared__ float red0[F2], red1[F2];
    int g = blockIdx.x;
    int t = threadIdx.x;
    int cntN = bounds[g + 1] - bounds[g];
    float cnt = fmaxf((float)cntN, 1.0f);
    float sum = 0.f;
    for (int s = 0; s < POOL_SPLITS; s++)
        sum += partial[((long)g * POOL_SPLITS + s) * F2 + t];
    float p = sum / cnt;
    red0[t] = p * Wout[t * 2 + 0];
    red1[t] = p * Wout[t * 2 + 1];
    __syncthreads();
    for (int off = F2 / 2; off > 0; off >>= 1) {
        if (t < off) { red0[t] += red0[t + off]; red1[t] += red1[t + off]; }
        __syncthreads();
    }
    if (t == 0) {
        float l0 = red0[0] + bout[0];
        float l1 = red1[0] + bout[1];
        float m = fmaxf(l0, l1);
        float e0 = __expf(l0 - m), e1 = __expf(l1 - m);
        float inv = 1.f / (e0 + e1);
        out[g * 2 + 0] = e0 * inv;
        out[g * 2 + 1] = e1 * inv;
    }
}

extern "C" void kernel_launch(void* const* d_in, const int* in_sizes, int n_in,
                              void* d_out, int out_size, void* d_ws, size_t ws_size,
                              hipStream_t stream) {
    const float* x     = (const float*)d_in[0];
    const int*   ei    = (const int*)d_in[1];
    const int*   batch = (const int*)d_in[2];
    const float* W1    = (const float*)d_in[3];
    const float* asrc1 = (const float*)d_in[4];
    const float* adst1 = (const float*)d_in[5];
    const float* b1    = (const float*)d_in[6];
    const float* W2    = (const float*)d_in[7];
    const float* asrc2 = (const float*)d_in[8];
    const float* adst2 = (const float*)d_in[9];
    const float* b2    = (const float*)d_in[10];
    const float* Wout  = (const float*)d_in[11];
    const float* bout  = (const float*)d_in[12];

    char* ws = (char*)d_ws;
    size_t off = 0;
    auto alloc = [&](size_t bytes) -> void* {
        void* p = ws + off;
        off += (bytes + 255) / 256 * 256;
        return p;
    };
    unsigned char* u_h = (unsigned char*)alloc((size_t)N_NODES * F1);  // fp8 h (both layers)
    ushortT* u_x1  = (ushortT*)alloc(sizeof(ushortT) * (size_t)N_NODES * F1);
    ushortT* u_x2  = (ushortT*)alloc(sizeof(ushortT) * (size_t)N_NODES * F2);
    ushortT* xb    = (ushortT*)alloc(sizeof(ushortT) * (size_t)N_NODES * IN_CH);
    uint4*   wpk   = (uint4*)alloc(sizeof(uint4) * 8192);  // W1|W2 fragment images
    float*   f_s   = (float*)alloc(sizeof(float) * (size_t)N_NODES * HEADS);
    float*   f_d   = (float*)alloc(sizeof(float) * (size_t)N_NODES * HEADS);
    int*     i_cnt = (int*)alloc(sizeof(int) * (size_t)N_NODES);
    int*     i_off = (int*)alloc(sizeof(int) * (size_t)(N_NODES + 1));
    int*     i_rnk = (int*)alloc(sizeof(int) * (size_t)N_EDGES);
    int*     i_csr = (int*)alloc(sizeof(int) * (size_t)N_EDGES);
    int*     i_bnd = (int*)alloc(sizeof(int) * (size_t)(N_GRAPHS + 1));
    int*     i_bs  = (int*)alloc(sizeof(int) * SCAN_NB);
    int*     i_bb  = (int*)alloc(sizeof(int) * SCAN_NB);
    float*   f_prt = (float*)alloc(sizeof(float) * (size_t)N_GRAPHS * POOL_SPLITS * F2);
    (void)ws_size; (void)in_sizes; (void)n_in; (void)out_size;

    hipMemsetAsync(i_cnt, 0, sizeof(int) * N_NODES, stream);

    // one-time packs: W1/W2 -> bf16 fragment image, x -> bf16 rows
    k_pack<<<32 + XPACK_GRID, 256, 0, stream>>>(x, W1, W2, wpk, xb);

    // mega: gemm1 (prepacked W, no LDS, fp8 out) + CSR count-with-rank
    k_mega1<<<GEMM_GRID + COUNT_GRID, 256, 0, stream>>>(
        xb, wpk, asrc1, adst1, u_h, f_s, f_d, ei, i_cnt, i_rnk);

    // 2-phase scan (+bounds); atomic-free scatter using precomputed ranks
    k_scan1<<<SCAN_NB, SCAN_B, 0, stream>>>(i_cnt, i_off, i_bs);
    k_scan2<<<1, SCAN_B, 0, stream>>>(i_bs, i_bb, i_off, batch, i_bnd);
    k_scatter<<<COUNT_GRID, 256, 0, stream>>>(ei, i_off, i_bb, i_rnk, i_csr);

    int agg_grid = N_NODES / (4 * 2);  // 2 nodes/wave, 4 waves/block = 6250

    // Layer 1 aggregation (fp8 gather, 2 nodes per wave, VEC=8)
    k_agg<HID, 8, 4, 128><<<agg_grid, 256, 0, stream>>>(
        u_h, f_s, f_d, i_off, i_bb, i_csr, b1, u_x1);

    // Layer 2
    k_gemm2<<<GEMM_GRID, 256, 0, stream>>>(u_x1, wpk + 4096, asrc2, adst2,
                                           u_h, f_s, f_d);
    k_agg<OUT_CH, 4, 4, 128><<<agg_grid, 256, 0, stream>>>(
        u_h, f_s, f_d, i_off, i_bb, i_csr, b2, u_x2);

    // Pool (1024 blocks, machine-filling) + tiny head
    dim3 pgrid(N_GRAPHS, POOL_SPLITS);
    k_pool_partial<<<pgrid, F2, 0, stream>>>(u_x2, i_bnd, f_prt);
    k_head<<<N_GRAPHS, F2, 0, stream>>>(f_prt, i_bnd, Wout, bout, (float*)d_out);
}